// Round 3
// baseline (12186.791 us; speedup 1.0000x reference)
//
#include <hip/hip_runtime.h>

// Problem constants
#define BB 4
#define SS 32
#define CC 128
#define HH 16
#define WW 32
#define HID 128
#define DEPTH 2
#define CIN 256           // CC + HID
#define COUT 512          // 4*HID
#define K9 (CIN * 9)      // 2304
#define KH 1152           // HID*9 (also CC*9)
#define HW (HH * WW)      // 512
#define MM (BB * HW)      // 2048
#define MBIG (SS * BB * HW) // 65536

// ---------------------------------------------------------------------------
// Weight split+transpose:
//   conv_w [DEPTH][COUT][CIN][3][3] ->
//     wtx [DEPTH][KH][COUT]  (cin <  CC : x-part,  k = cin*9+tap)
//     wth [DEPTH][KH][COUT]  (cin >= CC : h-part,  k = (cin-CC)*9+tap)
// ---------------------------------------------------------------------------
__global__ void transpose_w_kernel(const float* __restrict__ w,
                                   float* __restrict__ wtx, float* __restrict__ wth) {
    int idx = blockIdx.x * 256 + threadIdx.x;
    if (idx >= DEPTH * K9 * COUT) return;
    int n = idx % COUT;
    int k = (idx / COUT) % K9;
    int d = idx / (COUT * K9);
    int cin = k / 9, tap = k % 9;
    float v = w[(((long)(d * COUT + n) * CIN + cin) * 9) + tap];
    if (cin < CC) wtx[((long)d * KH + (cin * 9 + tap)) * COUT + n] = v;
    else          wth[((long)d * KH + ((cin - CC) * 9 + tap)) * COUT + n] = v;
}

// ---------------------------------------------------------------------------
// Broadcast init_h/init_c[d] into [B][HID][HW] state buffers
// ---------------------------------------------------------------------------
__global__ void init_state_kernel(const float* __restrict__ ih, const float* __restrict__ ic,
                                  float* __restrict__ h, float* __restrict__ c, int d) {
    int idx = blockIdx.x * 256 + threadIdx.x;   // B*HID*HW = 262144
    int hid = (idx >> 9) & (HID - 1);
    h[idx] = ih[d * HID + hid];
    c[idx] = ic[d * HID + hid];
}

// ---------------------------------------------------------------------------
// Big feed-forward GEMM over ALL timesteps (x-part of the conv).
// Tile 128x128, BK=32, 256 threads, 8x8 acc, register-prefetch double buffer,
// float4 coalesced stores. grid = (512, 4).
// ---------------------------------------------------------------------------
__launch_bounds__(256, 2)
__global__ void big_gemm_kernel(const float* __restrict__ xin, long strideS, long strideB,
                                const float* __restrict__ wt,   // [KH][COUT]
                                float* __restrict__ zx) {
    __shared__ __align__(16) float As[32][128];
    __shared__ __align__(16) float Bs[32][128];

    const int m0 = blockIdx.x * 128;
    const int n0 = blockIdx.y * 128;
    const int tid = threadIdx.x;
    const int tx = tid & 15;        // m
    const int ty = tid >> 4;        // n
    const int sb  = m0 >> 9;        // (s*B + b)
    const int s   = sb >> 2;
    const int b   = sb & 3;
    const int hw0 = m0 & 511;
    const float* img = xin + (long)s * strideS + (long)b * strideB;  // [128][HW]

    float acc[8][8] = {};
    float pa[16], pb[16];

    auto loadA = [&](int k0) {
        #pragma unroll
        for (int i = 0; i < 16; ++i) {
            int idx = i * 256 + tid;        // 0..4095
            int kk = idx >> 7;              // 0..31
            int m  = idx & 127;
            int k  = k0 + kk;
            int cin = k / 9;
            int tap = k - cin * 9;
            int ky = tap / 3 - 1;
            int kx = tap - (tap / 3) * 3 - 1;
            int hw = hw0 + m;
            int y  = hw >> 5, xx = hw & 31;
            int yy = y + ky, xq = xx + kx;
            float v = 0.f;
            if ((unsigned)yy < (unsigned)HH && (unsigned)xq < (unsigned)WW)
                v = img[cin * HW + yy * WW + xq];
            pa[i] = v;
        }
    };
    auto loadB = [&](int k0) {
        #pragma unroll
        for (int i = 0; i < 16; ++i) {
            int idx = i * 256 + tid;
            int kk = idx >> 7;
            int n  = idx & 127;
            pb[i] = wt[(long)(k0 + kk) * COUT + n0 + n];
        }
    };
    auto commit = [&]() {
        #pragma unroll
        for (int i = 0; i < 16; ++i) {
            int idx = i * 256 + tid;
            int kk = idx >> 7;
            int mn = idx & 127;
            As[kk][mn] = pa[i];
            Bs[kk][mn] = pb[i];
        }
    };

    loadA(0); loadB(0);
    commit();
    __syncthreads();

    for (int k0 = 0; k0 < KH; k0 += 32) {
        const bool more = (k0 + 32 < KH);
        if (more) { loadA(k0 + 32); loadB(k0 + 32); }

        #pragma unroll
        for (int kk = 0; kk < 32; ++kk) {
            float4 a0 = *(const float4*)&As[kk][tx * 4];
            float4 a1 = *(const float4*)&As[kk][64 + tx * 4];
            float4 b0 = *(const float4*)&Bs[kk][ty * 4];
            float4 b1 = *(const float4*)&Bs[kk][64 + ty * 4];
            float av[8] = {a0.x, a0.y, a0.z, a0.w, a1.x, a1.y, a1.z, a1.w};
            float bv[8] = {b0.x, b0.y, b0.z, b0.w, b1.x, b1.y, b1.z, b1.w};
            #pragma unroll
            for (int i = 0; i < 8; ++i)
                #pragma unroll
                for (int j = 0; j < 8; ++j)
                    acc[i][j] += av[i] * bv[j];
        }
        __syncthreads();
        if (more) {
            commit();
            __syncthreads();
        }
    }

    const long outbase = (long)sb * COUT * HW;
    #pragma unroll
    for (int j = 0; j < 8; ++j) {
        int n = n0 + ((j < 4) ? (ty * 4 + j) : (64 + ty * 4 + j - 4));
        float4 v0 = make_float4(acc[0][j], acc[1][j], acc[2][j], acc[3][j]);
        float4 v1 = make_float4(acc[4][j], acc[5][j], acc[6][j], acc[7][j]);
        *(float4*)&zx[outbase + (long)n * HW + hw0 + tx * 4]      = v0;
        *(float4*)&zx[outbase + (long)n * HW + hw0 + 64 + tx * 4] = v1;
    }
}

// ---------------------------------------------------------------------------
// Per-step recurrent GEMM (h-part only, K=1152), split-K=4 (288 each).
// Tile 64x64, BK=32, 256 threads, 4x4 acc, register-prefetch double buffer,
// float4 stores. grid = (32, 8, 4) = 1024 wgs.
// ---------------------------------------------------------------------------
__launch_bounds__(256)
__global__ void step_gemm_h(const float* __restrict__ hprev,   // [B][HID][HW]
                            const float* __restrict__ wth,     // [KH][COUT]
                            float* __restrict__ part) {
    __shared__ __align__(16) float As[32][64];
    __shared__ __align__(16) float Bs[32][64];

    const int m0 = blockIdx.x * 64;
    const int n0 = blockIdx.y * 64;
    const int kc = blockIdx.z;
    const int tid = threadIdx.x;
    const int tx = tid & 15;
    const int ty = tid >> 4;

    float acc[4][4] = {};
    float pa[8], pb[8];

    auto loadA = [&](int k0) {
        #pragma unroll
        for (int i = 0; i < 8; ++i) {
            int idx = i * 256 + tid;
            int kk = idx >> 6;
            int m  = idx & 63;
            int k  = k0 + kk;
            int cin = k / 9;
            int tap = k - cin * 9;
            int ky = tap / 3 - 1;
            int kx = tap - (tap / 3) * 3 - 1;
            int mm = m0 + m;
            int b  = mm >> 9;
            int y  = (mm >> 5) & 15;
            int xx = mm & 31;
            int yy = y + ky, xq = xx + kx;
            float v = 0.f;
            if ((unsigned)yy < (unsigned)HH && (unsigned)xq < (unsigned)WW)
                v = hprev[((long)(b * HID + cin)) * HW + yy * WW + xq];
            pa[i] = v;
        }
    };
    auto loadB = [&](int k0) {
        #pragma unroll
        for (int i = 0; i < 8; ++i) {
            int idx = i * 256 + tid;
            int kk = idx >> 6;
            int n  = idx & 63;
            pb[i] = wth[(long)(k0 + kk) * COUT + n0 + n];
        }
    };
    auto commit = [&]() {
        #pragma unroll
        for (int i = 0; i < 8; ++i) {
            int idx = i * 256 + tid;
            int kk = idx >> 6;
            int mn = idx & 63;
            As[kk][mn] = pa[i];
            Bs[kk][mn] = pb[i];
        }
    };

    const int kbase = kc * 288;
    loadA(kbase); loadB(kbase);
    commit();
    __syncthreads();

    for (int k0i = 0; k0i < 288; k0i += 32) {
        const bool more = (k0i + 32 < 288);
        if (more) { loadA(kbase + k0i + 32); loadB(kbase + k0i + 32); }

        #pragma unroll
        for (int kk = 0; kk < 32; ++kk) {
            float4 a = *(const float4*)&As[kk][tx * 4];
            float4 b = *(const float4*)&Bs[kk][ty * 4];
            acc[0][0] += a.x * b.x; acc[0][1] += a.x * b.y; acc[0][2] += a.x * b.z; acc[0][3] += a.x * b.w;
            acc[1][0] += a.y * b.x; acc[1][1] += a.y * b.y; acc[1][2] += a.y * b.z; acc[1][3] += a.y * b.w;
            acc[2][0] += a.z * b.x; acc[2][1] += a.z * b.y; acc[2][2] += a.z * b.z; acc[2][3] += a.z * b.w;
            acc[3][0] += a.w * b.x; acc[3][1] += a.w * b.y; acc[3][2] += a.w * b.z; acc[3][3] += a.w * b.w;
        }
        __syncthreads();
        if (more) {
            commit();
            __syncthreads();
        }
    }

    const long pbase = ((long)kc * BB) * COUT * HW;
    const int mm = m0 + tx * 4;
    const int b  = mm >> 9;
    const int hw = mm & 511;
    #pragma unroll
    for (int j = 0; j < 4; ++j) {
        int n = n0 + ty * 4 + j;
        float4 v = make_float4(acc[0][j], acc[1][j], acc[2][j], acc[3][j]);
        *(float4*)&part[pbase + ((long)b * COUT + n) * HW + hw] = v;
    }
}

// ---------------------------------------------------------------------------
// Fused split-K reduce + zx + bias + LSTM cell update.
// ---------------------------------------------------------------------------
__global__ void lstm_gate_fused(const float* __restrict__ part,  // [4][B][COUT][HW]
                                const float* __restrict__ zx,    // [B][COUT][HW] (step slice)
                                const float* __restrict__ bias,  // [COUT]
                                float* __restrict__ h, float* __restrict__ c,
                                float* __restrict__ seq_out) {
    const long PSTR = (long)BB * COUT * HW;
    int idx = blockIdx.x * 256 + threadIdx.x;     // over B*HID*HW = 262144
    int hw  = idx & 511;
    int hid = (idx >> 9) & (HID - 1);
    int b   = idx >> 16;
    long base = (long)b * COUT * HW + hw;
    float g[4];
    #pragma unroll
    for (int gi = 0; gi < 4; ++gi) {
        long o = base + (long)(hid + gi * HID) * HW;
        float v = zx[o] + bias[hid + gi * HID];
        v += part[o];
        v += part[o + PSTR];
        v += part[o + 2 * PSTR];
        v += part[o + 3 * PSTR];
        g[gi] = v;
    }
    float si = 1.f / (1.f + expf(-g[0]));
    float sf = 1.f / (1.f + expf(-g[1]));
    float so = 1.f / (1.f + expf(-g[3]));
    float cs = sf * c[idx] + si * tanhf(g[2]);
    float hs = so * tanhf(cs);
    c[idx] = cs;
    h[idx] = hs;
    seq_out[idx] = hs;
}

// ---------------------------------------------------------------------------
// Mean pool over HW: seq [S][B][HID][HW] -> pooled [S*B*HID]
// ---------------------------------------------------------------------------
__global__ void pool_kernel(const float* __restrict__ seq, float* __restrict__ pooled) {
    int row  = blockIdx.x * 4 + (threadIdx.x >> 6);
    int lane = threadIdx.x & 63;
    const float* p = seq + (long)row * HW;
    float sum = 0.f;
    #pragma unroll
    for (int i = 0; i < HW / 64; ++i) sum += p[lane + i * 64];
    #pragma unroll
    for (int off = 32; off; off >>= 1) sum += __shfl_down(sum, off);
    if (lane == 0) pooled[row] = sum * (1.f / HW);
}

// ---------------------------------------------------------------------------
// FC + ReLU + two scalar heads.
// ---------------------------------------------------------------------------
__global__ void head_kernel(const float* __restrict__ pooled,
                            const float* __restrict__ fc_w, const float* __restrict__ fc_b,
                            const float* __restrict__ fco_w, const float* __restrict__ fco_b,
                            const float* __restrict__ fca_w, const float* __restrict__ fca_b,
                            float* __restrict__ out) {
    int bs = blockIdx.x;          // b*S + s
    int b  = bs / SS;
    int s  = bs % SS;
    int j  = threadIdx.x;
    const float* prow = pooled + (long)(s * BB + b) * HID;
    float acc = fc_b[j];
    #pragma unroll 4
    for (int k = 0; k < HID; ++k) acc += fc_w[j * HID + k] * prow[k];
    float f = fmaxf(acc, 0.f);
    __shared__ float ro[128], ra[128];
    ro[j] = f * fco_w[j];
    ra[j] = f * fca_w[j];
    __syncthreads();
    for (int off = 64; off; off >>= 1) {
        if (j < off) { ro[j] += ro[j + off]; ra[j] += ra[j + off]; }
        __syncthreads();
    }
    if (j == 0) {
        out[bs]           = ro[0] + fco_b[0];
        out[BB * SS + bs] = ra[0] + fca_b[0];
    }
}

// ---------------------------------------------------------------------------
extern "C" void kernel_launch(void* const* d_in, const int* in_sizes, int n_in,
                              void* d_out, int out_size, void* d_ws, size_t ws_size,
                              hipStream_t stream) {
    const float* x      = (const float*)d_in[0];
    const float* conv_w = (const float*)d_in[1];
    const float* conv_b = (const float*)d_in[2];
    const float* init_h = (const float*)d_in[3];
    const float* init_c = (const float*)d_in[4];
    const float* fc_w   = (const float*)d_in[5];
    const float* fc_b   = (const float*)d_in[6];
    const float* fco_w  = (const float*)d_in[7];
    const float* fco_b  = (const float*)d_in[8];
    const float* fca_w  = (const float*)d_in[9];
    const float* fca_b  = (const float*)d_in[10];
    float* out = (float*)d_out;

    // Workspace carve-up (floats), total ~49.0M floats = ~196 MB.
    float* ws     = (float*)d_ws;
    float* wtx    = ws;                                   // DEPTH*KH*COUT = 1,179,648
    float* wth    = wtx  + (long)DEPTH * KH * COUT;       // 1,179,648
    float* zx     = wth  + (long)DEPTH * KH * COUT;       // S*B*COUT*HW  = 33,554,432
    float* seq    = zx   + (long)SS * BB * COUT * HW;     // S*B*HID*HW   = 8,388,608
    float* part   = seq  + (long)SS * BB * HID * HW;      // 4*B*COUT*HW  = 4,194,304
    float* hbuf   = part + (long)4 * BB * COUT * HW;      // 262,144
    float* cbuf   = hbuf + (long)BB * HID * HW;           // 262,144
    float* pooled = cbuf + (long)BB * HID * HW;           // 16,384

    transpose_w_kernel<<<(DEPTH * K9 * COUT + 255) / 256, 256, 0, stream>>>(conv_w, wtx, wth);

    const long ZSTEP = (long)BB * COUT * HW;
    const long QSTEP = (long)BB * HID * HW;

    for (int d = 0; d < DEPTH; ++d) {
        // x-part of the conv for ALL timesteps: one big parallel GEMM
        if (d == 0)
            big_gemm_kernel<<<dim3(MBIG / 128, COUT / 128), 256, 0, stream>>>(
                x, (long)CC * HW, (long)SS * CC * HW, wtx, zx);
        else
            big_gemm_kernel<<<dim3(MBIG / 128, COUT / 128), 256, 0, stream>>>(
                seq, (long)BB * HID * HW, (long)HID * HW, wtx + (long)KH * COUT, zx);

        init_state_kernel<<<(BB * HID * HW) / 256, 256, 0, stream>>>(init_h, init_c, hbuf, cbuf, d);

        const float* wth_d  = wth + (long)d * KH * COUT;
        const float* bias_d = conv_b + d * COUT;
        for (int s = 0; s < SS; ++s) {
            step_gemm_h<<<dim3(MM / 64, COUT / 64, 4), 256, 0, stream>>>(hbuf, wth_d, part);
            lstm_gate_fused<<<(BB * HID * HW) / 256, 256, 0, stream>>>(
                part, zx + (long)s * ZSTEP, bias_d, hbuf, cbuf, seq + (long)s * QSTEP);
        }
    }
    pool_kernel<<<(SS * BB * HID) / 4, 256, 0, stream>>>(seq, pooled);
    head_kernel<<<BB * SS, 128, 0, stream>>>(pooled, fc_w, fc_b, fco_w, fco_b, fca_w, fca_b, out);
}

// Round 4
// 5724.871 us; speedup vs baseline: 2.1287x; 2.1287x over previous
//
#include <hip/hip_runtime.h>

// Problem constants
#define BB 4
#define SS 32
#define CC 128
#define HH 16
#define WW 32
#define HID 128
#define DEPTH 2
#define CIN 256           // CC + HID
#define COUT 512          // 4*HID
#define K9 (CIN * 9)      // 2304
#define KH 1152           // 9*128 (tap-major: k = tap*128 + cin)
#define HW (HH * WW)      // 512
#define MM (BB * HW)      // 2048
#define MBIG (SS * BB * HW) // 65536

// ---------------------------------------------------------------------------
// Weight split+transpose (tap-major k):
//   conv_w [DEPTH][COUT][CIN][3][3] ->
//     wtx [DEPTH][KH][COUT]  (cin <  CC : k = tap*CC  + cin)
//     wth [DEPTH][KH][COUT]  (cin >= CC : k = tap*HID + (cin-CC))
// ---------------------------------------------------------------------------
__global__ void transpose_w_kernel(const float* __restrict__ w,
                                   float* __restrict__ wtx, float* __restrict__ wth) {
    int idx = blockIdx.x * 256 + threadIdx.x;
    if (idx >= DEPTH * K9 * COUT) return;
    int n = idx % COUT;
    int k = (idx / COUT) % K9;
    int d = idx / (COUT * K9);
    int cin = k / 9, tap = k % 9;
    float v = w[(((long)(d * COUT + n) * CIN + cin) * 9) + tap];
    if (cin < CC) wtx[((long)d * KH + (tap * CC + cin)) * COUT + n] = v;
    else          wth[((long)d * KH + (tap * HID + (cin - CC))) * COUT + n] = v;
}

// ---------------------------------------------------------------------------
// Broadcast init_h/init_c[d] into [B][HID][HW] state buffers
// ---------------------------------------------------------------------------
__global__ void init_state_kernel(const float* __restrict__ ih, const float* __restrict__ ic,
                                  float* __restrict__ h, float* __restrict__ c, int d) {
    int idx = blockIdx.x * 256 + threadIdx.x;   // B*HID*HW = 262144
    int hid = (idx >> 9) & (HID - 1);
    h[idx] = ih[d * HID + hid];
    c[idx] = ic[d * HID + hid];
}

// ---------------------------------------------------------------------------
// Big feed-forward GEMM over ALL timesteps (x-part of the conv).
// Tile 128x128, BK=32, 256 threads, 8x8 acc, single-buffered LDS,
// tap-major k (no div/mod in hot loop), float4 stores. grid = (512, 4).
// ---------------------------------------------------------------------------
__launch_bounds__(256, 2)
__global__ void big_gemm_kernel(const float* __restrict__ xin, long strideS, long strideB,
                                const float* __restrict__ wt,   // [KH][COUT] tap-major
                                float* __restrict__ zx) {
    __shared__ __align__(16) float As[32][128];
    __shared__ __align__(16) float Bs[32][128];

    const int m0 = blockIdx.x * 128;
    const int n0 = blockIdx.y * 128;
    const int tid = threadIdx.x;
    const int tx = tid & 15;        // m
    const int ty = tid >> 4;        // n
    const int sb  = m0 >> 9;        // (s*B + b)
    const int s   = sb >> 2;
    const int b   = sb & 3;
    const int hw0 = m0 & 511;
    const float* img = xin + (long)s * strideS + (long)b * strideB;  // [128][HW]

    float acc[8][8] = {};

    for (int k0 = 0; k0 < KH; k0 += 32) {
        const int tap = k0 >> 7;          // uniform per tile
        const int c0  = k0 & 127;
        const int ky  = tap / 3 - 1;
        const int kx  = tap - (tap / 3) * 3 - 1;
        #pragma unroll
        for (int i = 0; i < 16; ++i) {
            int idx = i * 256 + tid;        // 0..4095
            int kk = idx >> 7;              // 0..31
            int m  = idx & 127;
            int hw = hw0 + m;
            int yy = (hw >> 5) + ky;
            int xq = (hw & 31) + kx;
            float v = 0.f;
            if ((unsigned)yy < (unsigned)HH && (unsigned)xq < (unsigned)WW)
                v = img[(c0 + kk) * HW + yy * WW + xq];
            As[kk][m] = v;
        }
        #pragma unroll
        for (int i = 0; i < 16; ++i) {
            int idx = i * 256 + tid;
            int kk = idx >> 7;
            int n  = idx & 127;
            Bs[kk][n] = wt[(long)(k0 + kk) * COUT + n0 + n];
        }
        __syncthreads();

        #pragma unroll
        for (int kk = 0; kk < 32; ++kk) {
            float4 a0 = *(const float4*)&As[kk][tx * 4];
            float4 a1 = *(const float4*)&As[kk][64 + tx * 4];
            float4 b0 = *(const float4*)&Bs[kk][ty * 4];
            float4 b1 = *(const float4*)&Bs[kk][64 + ty * 4];
            float av[8] = {a0.x, a0.y, a0.z, a0.w, a1.x, a1.y, a1.z, a1.w};
            float bv[8] = {b0.x, b0.y, b0.z, b0.w, b1.x, b1.y, b1.z, b1.w};
            #pragma unroll
            for (int i = 0; i < 8; ++i)
                #pragma unroll
                for (int j = 0; j < 8; ++j)
                    acc[i][j] += av[i] * bv[j];
        }
        __syncthreads();
    }

    const long outbase = (long)sb * COUT * HW;
    #pragma unroll
    for (int j = 0; j < 8; ++j) {
        int n = n0 + ((j < 4) ? (ty * 4 + j) : (64 + ty * 4 + j - 4));
        float4 v0 = make_float4(acc[0][j], acc[1][j], acc[2][j], acc[3][j]);
        float4 v1 = make_float4(acc[4][j], acc[5][j], acc[6][j], acc[7][j]);
        *(float4*)&zx[outbase + (long)n * HW + hw0 + tx * 4]      = v0;
        *(float4*)&zx[outbase + (long)n * HW + hw0 + 64 + tx * 4] = v1;
    }
}

// ---------------------------------------------------------------------------
// Per-step recurrent GEMM (h-part only, K=1152), split-K=4 (288 each).
// Tile 64x64, BK=32, 256 threads, 4x4 acc, register-prefetch double buffer
// (no VGPR cap -> no spill), tap-major k, float4 stores. grid = (32,8,4).
// ---------------------------------------------------------------------------
__global__ void step_gemm_h(const float* __restrict__ hprev,   // [B][HID][HW]
                            const float* __restrict__ wth,     // [KH][COUT] tap-major
                            float* __restrict__ part) {
    __shared__ __align__(16) float As[32][64];
    __shared__ __align__(16) float Bs[32][64];

    const int m0 = blockIdx.x * 64;
    const int n0 = blockIdx.y * 64;
    const int kc = blockIdx.z;
    const int tid = threadIdx.x;
    const int tx = tid & 15;
    const int ty = tid >> 4;

    float acc[4][4] = {};
    float pa[8], pb[8];

    auto loadA = [&](int k0) {
        const int tap = k0 >> 7;
        const int c0  = k0 & 127;
        const int ky  = tap / 3 - 1;
        const int kx  = tap - (tap / 3) * 3 - 1;
        #pragma unroll
        for (int i = 0; i < 8; ++i) {
            int idx = i * 256 + tid;
            int kk = idx >> 6;
            int m  = idx & 63;
            int mm = m0 + m;
            int b  = mm >> 9;
            int yy = ((mm >> 5) & 15) + ky;
            int xq = (mm & 31) + kx;
            float v = 0.f;
            if ((unsigned)yy < (unsigned)HH && (unsigned)xq < (unsigned)WW)
                v = hprev[((long)(b * HID + c0 + kk)) * HW + yy * WW + xq];
            pa[i] = v;
        }
    };
    auto loadB = [&](int k0) {
        #pragma unroll
        for (int i = 0; i < 8; ++i) {
            int idx = i * 256 + tid;
            int kk = idx >> 6;
            int n  = idx & 63;
            pb[i] = wth[(long)(k0 + kk) * COUT + n0 + n];
        }
    };
    auto commit = [&]() {
        #pragma unroll
        for (int i = 0; i < 8; ++i) {
            int idx = i * 256 + tid;
            int kk = idx >> 6;
            int mn = idx & 63;
            As[kk][mn] = pa[i];
            Bs[kk][mn] = pb[i];
        }
    };

    const int kbase = kc * 288;
    loadA(kbase); loadB(kbase);
    commit();
    __syncthreads();

    for (int k0i = 0; k0i < 288; k0i += 32) {
        const bool more = (k0i + 32 < 288);
        if (more) { loadA(kbase + k0i + 32); loadB(kbase + k0i + 32); }

        #pragma unroll
        for (int kk = 0; kk < 32; ++kk) {
            float4 a = *(const float4*)&As[kk][tx * 4];
            float4 b = *(const float4*)&Bs[kk][ty * 4];
            acc[0][0] += a.x * b.x; acc[0][1] += a.x * b.y; acc[0][2] += a.x * b.z; acc[0][3] += a.x * b.w;
            acc[1][0] += a.y * b.x; acc[1][1] += a.y * b.y; acc[1][2] += a.y * b.z; acc[1][3] += a.y * b.w;
            acc[2][0] += a.z * b.x; acc[2][1] += a.z * b.y; acc[2][2] += a.z * b.z; acc[2][3] += a.z * b.w;
            acc[3][0] += a.w * b.x; acc[3][1] += a.w * b.y; acc[3][2] += a.w * b.z; acc[3][3] += a.w * b.w;
        }
        __syncthreads();
        if (more) {
            commit();
            __syncthreads();
        }
    }

    const long pbase = ((long)kc * BB) * COUT * HW;
    const int mm = m0 + tx * 4;
    const int b  = mm >> 9;
    const int hw = mm & 511;
    #pragma unroll
    for (int j = 0; j < 4; ++j) {
        int n = n0 + ty * 4 + j;
        float4 v = make_float4(acc[0][j], acc[1][j], acc[2][j], acc[3][j]);
        *(float4*)&part[pbase + ((long)b * COUT + n) * HW + hw] = v;
    }
}

// ---------------------------------------------------------------------------
// Fused split-K reduce + zx + bias + LSTM cell update.
// ---------------------------------------------------------------------------
__global__ void lstm_gate_fused(const float* __restrict__ part,  // [4][B][COUT][HW]
                                const float* __restrict__ zx,    // [B][COUT][HW] (step slice)
                                const float* __restrict__ bias,  // [COUT]
                                float* __restrict__ h, float* __restrict__ c,
                                float* __restrict__ seq_out) {
    const long PSTR = (long)BB * COUT * HW;
    int idx = blockIdx.x * 256 + threadIdx.x;     // over B*HID*HW = 262144
    int hw  = idx & 511;
    int hid = (idx >> 9) & (HID - 1);
    int b   = idx >> 16;
    long base = (long)b * COUT * HW + hw;
    float g[4];
    #pragma unroll
    for (int gi = 0; gi < 4; ++gi) {
        long o = base + (long)(hid + gi * HID) * HW;
        float v = zx[o] + bias[hid + gi * HID];
        v += part[o];
        v += part[o + PSTR];
        v += part[o + 2 * PSTR];
        v += part[o + 3 * PSTR];
        g[gi] = v;
    }
    float si = 1.f / (1.f + expf(-g[0]));
    float sf = 1.f / (1.f + expf(-g[1]));
    float so = 1.f / (1.f + expf(-g[3]));
    float cs = sf * c[idx] + si * tanhf(g[2]);
    float hs = so * tanhf(cs);
    c[idx] = cs;
    h[idx] = hs;
    seq_out[idx] = hs;
}

// ---------------------------------------------------------------------------
// Mean pool over HW: seq [S][B][HID][HW] -> pooled [S*B*HID]
// ---------------------------------------------------------------------------
__global__ void pool_kernel(const float* __restrict__ seq, float* __restrict__ pooled) {
    int row  = blockIdx.x * 4 + (threadIdx.x >> 6);
    int lane = threadIdx.x & 63;
    const float* p = seq + (long)row * HW;
    float sum = 0.f;
    #pragma unroll
    for (int i = 0; i < HW / 64; ++i) sum += p[lane + i * 64];
    #pragma unroll
    for (int off = 32; off; off >>= 1) sum += __shfl_down(sum, off);
    if (lane == 0) pooled[row] = sum * (1.f / HW);
}

// ---------------------------------------------------------------------------
// FC + ReLU + two scalar heads.
// ---------------------------------------------------------------------------
__global__ void head_kernel(const float* __restrict__ pooled,
                            const float* __restrict__ fc_w, const float* __restrict__ fc_b,
                            const float* __restrict__ fco_w, const float* __restrict__ fco_b,
                            const float* __restrict__ fca_w, const float* __restrict__ fca_b,
                            float* __restrict__ out) {
    int bs = blockIdx.x;          // b*S + s
    int b  = bs / SS;
    int s  = bs % SS;
    int j  = threadIdx.x;
    const float* prow = pooled + (long)(s * BB + b) * HID;
    float acc = fc_b[j];
    #pragma unroll 4
    for (int k = 0; k < HID; ++k) acc += fc_w[j * HID + k] * prow[k];
    float f = fmaxf(acc, 0.f);
    __shared__ float ro[128], ra[128];
    ro[j] = f * fco_w[j];
    ra[j] = f * fca_w[j];
    __syncthreads();
    for (int off = 64; off; off >>= 1) {
        if (j < off) { ro[j] += ro[j + off]; ra[j] += ra[j + off]; }
        __syncthreads();
    }
    if (j == 0) {
        out[bs]           = ro[0] + fco_b[0];
        out[BB * SS + bs] = ra[0] + fca_b[0];
    }
}

// ---------------------------------------------------------------------------
extern "C" void kernel_launch(void* const* d_in, const int* in_sizes, int n_in,
                              void* d_out, int out_size, void* d_ws, size_t ws_size,
                              hipStream_t stream) {
    const float* x      = (const float*)d_in[0];
    const float* conv_w = (const float*)d_in[1];
    const float* conv_b = (const float*)d_in[2];
    const float* init_h = (const float*)d_in[3];
    const float* init_c = (const float*)d_in[4];
    const float* fc_w   = (const float*)d_in[5];
    const float* fc_b   = (const float*)d_in[6];
    const float* fco_w  = (const float*)d_in[7];
    const float* fco_b  = (const float*)d_in[8];
    const float* fca_w  = (const float*)d_in[9];
    const float* fca_b  = (const float*)d_in[10];
    float* out = (float*)d_out;

    // Workspace carve-up (floats), total ~49.0M floats = ~196 MB.
    float* ws     = (float*)d_ws;
    float* wtx    = ws;                                   // DEPTH*KH*COUT = 1,179,648
    float* wth    = wtx  + (long)DEPTH * KH * COUT;       // 1,179,648
    float* zx     = wth  + (long)DEPTH * KH * COUT;       // S*B*COUT*HW  = 33,554,432
    float* seq    = zx   + (long)SS * BB * COUT * HW;     // S*B*HID*HW   = 8,388,608
    float* part   = seq  + (long)SS * BB * HID * HW;      // 4*B*COUT*HW  = 4,194,304
    float* hbuf   = part + (long)4 * BB * COUT * HW;      // 262,144
    float* cbuf   = hbuf + (long)BB * HID * HW;           // 262,144
    float* pooled = cbuf + (long)BB * HID * HW;           // 16,384

    transpose_w_kernel<<<(DEPTH * K9 * COUT + 255) / 256, 256, 0, stream>>>(conv_w, wtx, wth);

    const long ZSTEP = (long)BB * COUT * HW;
    const long QSTEP = (long)BB * HID * HW;

    for (int d = 0; d < DEPTH; ++d) {
        // x-part of the conv for ALL timesteps: one big parallel GEMM
        if (d == 0)
            big_gemm_kernel<<<dim3(MBIG / 128, COUT / 128), 256, 0, stream>>>(
                x, (long)CC * HW, (long)SS * CC * HW, wtx, zx);
        else
            big_gemm_kernel<<<dim3(MBIG / 128, COUT / 128), 256, 0, stream>>>(
                seq, (long)BB * HID * HW, (long)HID * HW, wtx + (long)KH * COUT, zx);

        init_state_kernel<<<(BB * HID * HW) / 256, 256, 0, stream>>>(init_h, init_c, hbuf, cbuf, d);

        const float* wth_d  = wth + (long)d * KH * COUT;
        const float* bias_d = conv_b + d * COUT;
        for (int s = 0; s < SS; ++s) {
            step_gemm_h<<<dim3(MM / 64, COUT / 64, 4), 256, 0, stream>>>(hbuf, wth_d, part);
            lstm_gate_fused<<<(BB * HID * HW) / 256, 256, 0, stream>>>(
                part, zx + (long)s * ZSTEP, bias_d, hbuf, cbuf, seq + (long)s * QSTEP);
        }
    }
    pool_kernel<<<(SS * BB * HID) / 4, 256, 0, stream>>>(seq, pooled);
    head_kernel<<<BB * SS, 128, 0, stream>>>(pooled, fc_w, fc_b, fco_w, fco_b, fca_w, fca_b, out);
}